// Round 1
// baseline (152.412 us; speedup 1.0000x reference)
//
#include <hip/hip_runtime.h>

// Problem constants (fixed by the reference)
constexpr int N    = 16384;
constexpr int K    = 32;
constexpr int D    = 128;
constexpr int ROWS = 64;          // rows per block
constexpr int SPAD = K + 4;       // padded LDS row (36) to break bank conflicts

__global__ __launch_bounds__(256) void enc_kernel(
    const float* __restrict__ x,      // (N, D)
    const float* __restrict__ codes,  // (K, D)
    const float* __restrict__ scale,  // (K,)
    float* __restrict__ out)          // (K, D), pre-zeroed
{
    __shared__ float sc_lds[ROWS][SPAD];  // raw scores l2*scale
    __shared__ float w_lds[ROWS][SPAD];   // softmax weights

    const int tid = threadIdx.x;
    const int k   = tid >> 3;   // 0..31  (codeword owned by this thread)
    const int dc  = tid & 7;    // 0..7   (d-chunk owned)
    const int d0  = dc << 4;    // 16 floats per chunk

    // codes fragment for (k, d0..d0+15) lives in registers for the whole kernel
    const float4 ck0 = *reinterpret_cast<const float4*>(&codes[k * D + d0 + 0]);
    const float4 ck1 = *reinterpret_cast<const float4*>(&codes[k * D + d0 + 4]);
    const float4 ck2 = *reinterpret_cast<const float4*>(&codes[k * D + d0 + 8]);
    const float4 ck3 = *reinterpret_cast<const float4*>(&codes[k * D + d0 + 12]);
    const float scl = scale[k];

    const long row0 = (long)blockIdx.x * ROWS;
    const float* xb = x + row0 * D + d0;   // base of this thread's d-chunk, row 0

    // ---------------- Phase 1: scores[n][k] = ||x_n - c_k|| * scale[k] ----------------
    #pragma unroll 4
    for (int n = 0; n < ROWS; ++n) {
        const float4* xr = reinterpret_cast<const float4*>(xb + (long)n * D);
        float4 x0 = xr[0], x1 = xr[1], x2 = xr[2], x3 = xr[3];
        float p = 0.f, r;
        r = x0.x - ck0.x; p = fmaf(r, r, p);
        r = x0.y - ck0.y; p = fmaf(r, r, p);
        r = x0.z - ck0.z; p = fmaf(r, r, p);
        r = x0.w - ck0.w; p = fmaf(r, r, p);
        r = x1.x - ck1.x; p = fmaf(r, r, p);
        r = x1.y - ck1.y; p = fmaf(r, r, p);
        r = x1.z - ck1.z; p = fmaf(r, r, p);
        r = x1.w - ck1.w; p = fmaf(r, r, p);
        r = x2.x - ck2.x; p = fmaf(r, r, p);
        r = x2.y - ck2.y; p = fmaf(r, r, p);
        r = x2.z - ck2.z; p = fmaf(r, r, p);
        r = x2.w - ck2.w; p = fmaf(r, r, p);
        r = x3.x - ck3.x; p = fmaf(r, r, p);
        r = x3.y - ck3.y; p = fmaf(r, r, p);
        r = x3.z - ck3.z; p = fmaf(r, r, p);
        r = x3.w - ck3.w; p = fmaf(r, r, p);
        // reduce over the 8 lanes (contiguous) sharing this k
        p += __shfl_xor(p, 1);
        p += __shfl_xor(p, 2);
        p += __shfl_xor(p, 4);
        if (dc == 0) sc_lds[n][k] = sqrtf(p) * scl;
    }
    __syncthreads();

    // ---------------- Softmax over K per row: 4 threads per row ----------------
    {
        const int row = tid >> 2;      // 0..63
        const int q   = tid & 3;       // 8 codewords per thread
        float4 s0 = *reinterpret_cast<const float4*>(&sc_lds[row][q * 8 + 0]);
        float4 s1 = *reinterpret_cast<const float4*>(&sc_lds[row][q * 8 + 4]);
        float m = fmaxf(fmaxf(fmaxf(s0.x, s0.y), fmaxf(s0.z, s0.w)),
                        fmaxf(fmaxf(s1.x, s1.y), fmaxf(s1.z, s1.w)));
        m = fmaxf(m, __shfl_xor(m, 1));
        m = fmaxf(m, __shfl_xor(m, 2));
        const float LOG2E = 1.44269504088896f;
        float e0 = exp2f((s0.x - m) * LOG2E);
        float e1 = exp2f((s0.y - m) * LOG2E);
        float e2 = exp2f((s0.z - m) * LOG2E);
        float e3 = exp2f((s0.w - m) * LOG2E);
        float e4 = exp2f((s1.x - m) * LOG2E);
        float e5 = exp2f((s1.y - m) * LOG2E);
        float e6 = exp2f((s1.z - m) * LOG2E);
        float e7 = exp2f((s1.w - m) * LOG2E);
        float sum = ((e0 + e1) + (e2 + e3)) + ((e4 + e5) + (e6 + e7));
        sum += __shfl_xor(sum, 1);
        sum += __shfl_xor(sum, 2);
        float inv = 1.0f / sum;
        float4 w0 = make_float4(e0 * inv, e1 * inv, e2 * inv, e3 * inv);
        float4 w1 = make_float4(e4 * inv, e5 * inv, e6 * inv, e7 * inv);
        *reinterpret_cast<float4*>(&w_lds[row][q * 8 + 0]) = w0;
        *reinterpret_cast<float4*>(&w_lds[row][q * 8 + 4]) = w1;
    }
    __syncthreads();

    // ---------------- Phase 2: T[k,d] = sum_n w*x ; S[k] = sum_n w ----------------
    float4 t0 = make_float4(0.f, 0.f, 0.f, 0.f);
    float4 t1 = t0, t2 = t0, t3 = t0;
    float sw = 0.f;
    #pragma unroll 4
    for (int n = 0; n < ROWS; ++n) {
        float w = w_lds[n][k];
        const float4* xr = reinterpret_cast<const float4*>(xb + (long)n * D);
        float4 x0 = xr[0], x1 = xr[1], x2 = xr[2], x3 = xr[3];
        t0.x = fmaf(w, x0.x, t0.x);
        t0.y = fmaf(w, x0.y, t0.y);
        t0.z = fmaf(w, x0.z, t0.z);
        t0.w = fmaf(w, x0.w, t0.w);
        t1.x = fmaf(w, x1.x, t1.x);
        t1.y = fmaf(w, x1.y, t1.y);
        t1.z = fmaf(w, x1.z, t1.z);
        t1.w = fmaf(w, x1.w, t1.w);
        t2.x = fmaf(w, x2.x, t2.x);
        t2.y = fmaf(w, x2.y, t2.y);
        t2.z = fmaf(w, x2.z, t2.z);
        t2.w = fmaf(w, x2.w, t2.w);
        t3.x = fmaf(w, x3.x, t3.x);
        t3.y = fmaf(w, x3.y, t3.y);
        t3.z = fmaf(w, x3.z, t3.z);
        t3.w = fmaf(w, x3.w, t3.w);
        sw += w;
    }

    // ---------------- Epilogue: E = T - S*c, atomic into global ----------------
    float* o = out + k * D + d0;
    atomicAdd(&o[0],  t0.x - sw * ck0.x);
    atomicAdd(&o[1],  t0.y - sw * ck0.y);
    atomicAdd(&o[2],  t0.z - sw * ck0.z);
    atomicAdd(&o[3],  t0.w - sw * ck0.w);
    atomicAdd(&o[4],  t1.x - sw * ck1.x);
    atomicAdd(&o[5],  t1.y - sw * ck1.y);
    atomicAdd(&o[6],  t1.z - sw * ck1.z);
    atomicAdd(&o[7],  t1.w - sw * ck1.w);
    atomicAdd(&o[8],  t2.x - sw * ck2.x);
    atomicAdd(&o[9],  t2.y - sw * ck2.y);
    atomicAdd(&o[10], t2.z - sw * ck2.z);
    atomicAdd(&o[11], t2.w - sw * ck2.w);
    atomicAdd(&o[12], t3.x - sw * ck3.x);
    atomicAdd(&o[13], t3.y - sw * ck3.y);
    atomicAdd(&o[14], t3.z - sw * ck3.z);
    atomicAdd(&o[15], t3.w - sw * ck3.w);
}

extern "C" void kernel_launch(void* const* d_in, const int* in_sizes, int n_in,
                              void* d_out, int out_size, void* d_ws, size_t ws_size,
                              hipStream_t stream) {
    const float* x     = (const float*)d_in[0];
    const float* codes = (const float*)d_in[1];
    const float* scale = (const float*)d_in[2];
    float* out = (float*)d_out;

    hipMemsetAsync(out, 0, K * D * sizeof(float), stream);
    enc_kernel<<<N / ROWS, 256, 0, stream>>>(x, codes, scale, out);
}

// Round 2
// 52.382 us; speedup vs baseline: 2.9096x; 2.9096x over previous
//
#include <hip/hip_runtime.h>

// Problem constants (fixed by the reference)
constexpr int N    = 16384;
constexpr int K    = 32;
constexpr int D    = 128;
constexpr int SPAD = K + 4;       // padded LDS row (36) to break bank conflicts

// ------------------------------------------------------------------
// Stage 1: per-block partial E_b = T_b - S_b * c  -> ws[block][K*D]
// ROWS=16 rows per block, grid = N/16 = 1024 blocks (~4 blocks/CU).
// ------------------------------------------------------------------
constexpr int ROWS1 = 16;
constexpr int GRID1 = N / ROWS1;  // 1024

__global__ __launch_bounds__(256) void enc_partial(
    const float* __restrict__ x,      // (N, D)
    const float* __restrict__ codes,  // (K, D)
    const float* __restrict__ scale,  // (K,)
    float* __restrict__ ws)           // (GRID1, K*D)
{
    __shared__ float sc_lds[ROWS1][SPAD];  // raw scores l2*scale
    __shared__ float w_lds[ROWS1][SPAD];   // softmax weights

    const int tid = threadIdx.x;
    const int k   = tid >> 3;   // 0..31  (codeword owned by this thread)
    const int dc  = tid & 7;    // 0..7   (d-chunk owned)
    const int d0  = dc << 4;    // 16 floats per chunk

    // codes fragment for (k, d0..d0+15) in registers for the whole kernel
    const float4 ck0 = *reinterpret_cast<const float4*>(&codes[k * D + d0 + 0]);
    const float4 ck1 = *reinterpret_cast<const float4*>(&codes[k * D + d0 + 4]);
    const float4 ck2 = *reinterpret_cast<const float4*>(&codes[k * D + d0 + 8]);
    const float4 ck3 = *reinterpret_cast<const float4*>(&codes[k * D + d0 + 12]);
    const float scl = scale[k];

    const float* xb = x + (long)blockIdx.x * ROWS1 * D + d0;

    // ---------------- Phase 1: scores[n][k] = ||x_n - c_k|| * scale[k] ----------------
    #pragma unroll 4
    for (int n = 0; n < ROWS1; ++n) {
        const float4* xr = reinterpret_cast<const float4*>(xb + (long)n * D);
        float4 x0 = xr[0], x1 = xr[1], x2 = xr[2], x3 = xr[3];
        float p = 0.f, r;
        r = x0.x - ck0.x; p = fmaf(r, r, p);
        r = x0.y - ck0.y; p = fmaf(r, r, p);
        r = x0.z - ck0.z; p = fmaf(r, r, p);
        r = x0.w - ck0.w; p = fmaf(r, r, p);
        r = x1.x - ck1.x; p = fmaf(r, r, p);
        r = x1.y - ck1.y; p = fmaf(r, r, p);
        r = x1.z - ck1.z; p = fmaf(r, r, p);
        r = x1.w - ck1.w; p = fmaf(r, r, p);
        r = x2.x - ck2.x; p = fmaf(r, r, p);
        r = x2.y - ck2.y; p = fmaf(r, r, p);
        r = x2.z - ck2.z; p = fmaf(r, r, p);
        r = x2.w - ck2.w; p = fmaf(r, r, p);
        r = x3.x - ck3.x; p = fmaf(r, r, p);
        r = x3.y - ck3.y; p = fmaf(r, r, p);
        r = x3.z - ck3.z; p = fmaf(r, r, p);
        r = x3.w - ck3.w; p = fmaf(r, r, p);
        // reduce over the 8 contiguous lanes sharing this k
        p += __shfl_xor(p, 1);
        p += __shfl_xor(p, 2);
        p += __shfl_xor(p, 4);
        if (dc == 0) sc_lds[n][k] = sqrtf(p) * scl;
    }
    __syncthreads();

    // ---------------- Softmax over K per row: 16 threads/row, 2 k's each ----------------
    {
        const int row = tid >> 4;      // 0..15
        const int q   = tid & 15;
        float s0 = sc_lds[row][q];
        float s1 = sc_lds[row][q + 16];
        float m = fmaxf(s0, s1);
        m = fmaxf(m, __shfl_xor(m, 1));
        m = fmaxf(m, __shfl_xor(m, 2));
        m = fmaxf(m, __shfl_xor(m, 4));
        m = fmaxf(m, __shfl_xor(m, 8));
        const float LOG2E = 1.44269504088896f;
        float e0 = exp2f((s0 - m) * LOG2E);
        float e1 = exp2f((s1 - m) * LOG2E);
        float sum = e0 + e1;
        sum += __shfl_xor(sum, 1);
        sum += __shfl_xor(sum, 2);
        sum += __shfl_xor(sum, 4);
        sum += __shfl_xor(sum, 8);
        float inv = 1.0f / sum;
        w_lds[row][q]      = e0 * inv;
        w_lds[row][q + 16] = e1 * inv;
    }
    __syncthreads();

    // ---------------- Phase 2: T[k,d] = sum_n w*x ; S[k] = sum_n w ----------------
    float4 t0 = make_float4(0.f, 0.f, 0.f, 0.f);
    float4 t1 = t0, t2 = t0, t3 = t0;
    float sw = 0.f;
    #pragma unroll 4
    for (int n = 0; n < ROWS1; ++n) {
        float w = w_lds[n][k];
        const float4* xr = reinterpret_cast<const float4*>(xb + (long)n * D);
        float4 x0 = xr[0], x1 = xr[1], x2 = xr[2], x3 = xr[3];
        t0.x = fmaf(w, x0.x, t0.x);
        t0.y = fmaf(w, x0.y, t0.y);
        t0.z = fmaf(w, x0.z, t0.z);
        t0.w = fmaf(w, x0.w, t0.w);
        t1.x = fmaf(w, x1.x, t1.x);
        t1.y = fmaf(w, x1.y, t1.y);
        t1.z = fmaf(w, x1.z, t1.z);
        t1.w = fmaf(w, x1.w, t1.w);
        t2.x = fmaf(w, x2.x, t2.x);
        t2.y = fmaf(w, x2.y, t2.y);
        t2.z = fmaf(w, x2.z, t2.z);
        t2.w = fmaf(w, x2.w, t2.w);
        t3.x = fmaf(w, x3.x, t3.x);
        t3.y = fmaf(w, x3.y, t3.y);
        t3.z = fmaf(w, x3.z, t3.z);
        t3.w = fmaf(w, x3.w, t3.w);
        sw += w;
    }

    // ---------------- Epilogue: partial E_b = T - S*c -> ws (plain stores) ----------------
    // Note: k*D + d0 == tid*16, so each thread's 16 floats are contiguous.
    float* o = ws + (long)blockIdx.x * (K * D) + tid * 16;
    float4 e0 = make_float4(t0.x - sw * ck0.x, t0.y - sw * ck0.y,
                            t0.z - sw * ck0.z, t0.w - sw * ck0.w);
    float4 e1 = make_float4(t1.x - sw * ck1.x, t1.y - sw * ck1.y,
                            t1.z - sw * ck1.z, t1.w - sw * ck1.w);
    float4 e2 = make_float4(t2.x - sw * ck2.x, t2.y - sw * ck2.y,
                            t2.z - sw * ck2.z, t2.w - sw * ck2.w);
    float4 e3 = make_float4(t3.x - sw * ck3.x, t3.y - sw * ck3.y,
                            t3.z - sw * ck3.z, t3.w - sw * ck3.w);
    reinterpret_cast<float4*>(o)[0] = e0;
    reinterpret_cast<float4*>(o)[1] = e1;
    reinterpret_cast<float4*>(o)[2] = e2;
    reinterpret_cast<float4*>(o)[3] = e3;
}

// ------------------------------------------------------------------
// Stage 2: column-sum ws[1024][4096] -> out[4096]
// grid = 4 colgroups x 16 rowgroups = 64 blocks; float4 loads;
// 16 atomics per output address (negligible contention).
// ------------------------------------------------------------------
__global__ __launch_bounds__(256) void reduce_kernel(
    const float* __restrict__ ws, float* __restrict__ out)
{
    const int cg = blockIdx.x & 3;    // 4 groups of 256 float4-columns
    const int rg = blockIdx.x >> 2;   // 16 groups of 64 rows
    const int c4 = cg * 256 + threadIdx.x;   // float4 column 0..1023
    const float4* P = reinterpret_cast<const float4*>(ws);  // [1024][1024]
    float4 acc = make_float4(0.f, 0.f, 0.f, 0.f);
    long base = (long)rg * 64 * 1024 + c4;
    #pragma unroll 8
    for (int r = 0; r < 64; ++r) {
        float4 v = P[base + (long)r * 1024];
        acc.x += v.x; acc.y += v.y; acc.z += v.z; acc.w += v.w;
    }
    float* o = out + c4 * 4;
    atomicAdd(&o[0], acc.x);
    atomicAdd(&o[1], acc.y);
    atomicAdd(&o[2], acc.z);
    atomicAdd(&o[3], acc.w);
}

// ------------------------------------------------------------------
// Fallback (ws too small): round-1 direct-atomic kernel, 256 blocks.
// ------------------------------------------------------------------
constexpr int ROWSF = 64;

__global__ __launch_bounds__(256) void enc_atomic(
    const float* __restrict__ x,
    const float* __restrict__ codes,
    const float* __restrict__ scale,
    float* __restrict__ out)
{
    __shared__ float sc_lds[ROWSF][SPAD];
    __shared__ float w_lds[ROWSF][SPAD];

    const int tid = threadIdx.x;
    const int k   = tid >> 3;
    const int dc  = tid & 7;
    const int d0  = dc << 4;

    const float4 ck0 = *reinterpret_cast<const float4*>(&codes[k * D + d0 + 0]);
    const float4 ck1 = *reinterpret_cast<const float4*>(&codes[k * D + d0 + 4]);
    const float4 ck2 = *reinterpret_cast<const float4*>(&codes[k * D + d0 + 8]);
    const float4 ck3 = *reinterpret_cast<const float4*>(&codes[k * D + d0 + 12]);
    const float scl = scale[k];

    const float* xb = x + (long)blockIdx.x * ROWSF * D + d0;

    #pragma unroll 4
    for (int n = 0; n < ROWSF; ++n) {
        const float4* xr = reinterpret_cast<const float4*>(xb + (long)n * D);
        float4 x0 = xr[0], x1 = xr[1], x2 = xr[2], x3 = xr[3];
        float p = 0.f, r;
        r = x0.x - ck0.x; p = fmaf(r, r, p);
        r = x0.y - ck0.y; p = fmaf(r, r, p);
        r = x0.z - ck0.z; p = fmaf(r, r, p);
        r = x0.w - ck0.w; p = fmaf(r, r, p);
        r = x1.x - ck1.x; p = fmaf(r, r, p);
        r = x1.y - ck1.y; p = fmaf(r, r, p);
        r = x1.z - ck1.z; p = fmaf(r, r, p);
        r = x1.w - ck1.w; p = fmaf(r, r, p);
        r = x2.x - ck2.x; p = fmaf(r, r, p);
        r = x2.y - ck2.y; p = fmaf(r, r, p);
        r = x2.z - ck2.z; p = fmaf(r, r, p);
        r = x2.w - ck2.w; p = fmaf(r, r, p);
        r = x3.x - ck3.x; p = fmaf(r, r, p);
        r = x3.y - ck3.y; p = fmaf(r, r, p);
        r = x3.z - ck3.z; p = fmaf(r, r, p);
        r = x3.w - ck3.w; p = fmaf(r, r, p);
        p += __shfl_xor(p, 1);
        p += __shfl_xor(p, 2);
        p += __shfl_xor(p, 4);
        if (dc == 0) sc_lds[n][k] = sqrtf(p) * scl;
    }
    __syncthreads();

    {
        const int row = tid >> 2;
        const int q   = tid & 3;
        float4 s0 = *reinterpret_cast<const float4*>(&sc_lds[row][q * 8 + 0]);
        float4 s1 = *reinterpret_cast<const float4*>(&sc_lds[row][q * 8 + 4]);
        float m = fmaxf(fmaxf(fmaxf(s0.x, s0.y), fmaxf(s0.z, s0.w)),
                        fmaxf(fmaxf(s1.x, s1.y), fmaxf(s1.z, s1.w)));
        m = fmaxf(m, __shfl_xor(m, 1));
        m = fmaxf(m, __shfl_xor(m, 2));
        const float LOG2E = 1.44269504088896f;
        float e0 = exp2f((s0.x - m) * LOG2E);
        float e1 = exp2f((s0.y - m) * LOG2E);
        float e2 = exp2f((s0.z - m) * LOG2E);
        float e3 = exp2f((s0.w - m) * LOG2E);
        float e4 = exp2f((s1.x - m) * LOG2E);
        float e5 = exp2f((s1.y - m) * LOG2E);
        float e6 = exp2f((s1.z - m) * LOG2E);
        float e7 = exp2f((s1.w - m) * LOG2E);
        float sum = ((e0 + e1) + (e2 + e3)) + ((e4 + e5) + (e6 + e7));
        sum += __shfl_xor(sum, 1);
        sum += __shfl_xor(sum, 2);
        float inv = 1.0f / sum;
        *reinterpret_cast<float4*>(&w_lds[row][q * 8 + 0]) =
            make_float4(e0 * inv, e1 * inv, e2 * inv, e3 * inv);
        *reinterpret_cast<float4*>(&w_lds[row][q * 8 + 4]) =
            make_float4(e4 * inv, e5 * inv, e6 * inv, e7 * inv);
    }
    __syncthreads();

    float4 t0 = make_float4(0.f, 0.f, 0.f, 0.f);
    float4 t1 = t0, t2 = t0, t3 = t0;
    float sw = 0.f;
    #pragma unroll 4
    for (int n = 0; n < ROWSF; ++n) {
        float w = w_lds[n][k];
        const float4* xr = reinterpret_cast<const float4*>(xb + (long)n * D);
        float4 x0 = xr[0], x1 = xr[1], x2 = xr[2], x3 = xr[3];
        t0.x = fmaf(w, x0.x, t0.x);
        t0.y = fmaf(w, x0.y, t0.y);
        t0.z = fmaf(w, x0.z, t0.z);
        t0.w = fmaf(w, x0.w, t0.w);
        t1.x = fmaf(w, x1.x, t1.x);
        t1.y = fmaf(w, x1.y, t1.y);
        t1.z = fmaf(w, x1.z, t1.z);
        t1.w = fmaf(w, x1.w, t1.w);
        t2.x = fmaf(w, x2.x, t2.x);
        t2.y = fmaf(w, x2.y, t2.y);
        t2.z = fmaf(w, x2.z, t2.z);
        t2.w = fmaf(w, x2.w, t2.w);
        t3.x = fmaf(w, x3.x, t3.x);
        t3.y = fmaf(w, x3.y, t3.y);
        t3.z = fmaf(w, x3.z, t3.z);
        t3.w = fmaf(w, x3.w, t3.w);
        sw += w;
    }

    float* o = out + k * D + d0;
    atomicAdd(&o[0],  t0.x - sw * ck0.x);
    atomicAdd(&o[1],  t0.y - sw * ck0.y);
    atomicAdd(&o[2],  t0.z - sw * ck0.z);
    atomicAdd(&o[3],  t0.w - sw * ck0.w);
    atomicAdd(&o[4],  t1.x - sw * ck1.x);
    atomicAdd(&o[5],  t1.y - sw * ck1.y);
    atomicAdd(&o[6],  t1.z - sw * ck1.z);
    atomicAdd(&o[7],  t1.w - sw * ck1.w);
    atomicAdd(&o[8],  t2.x - sw * ck2.x);
    atomicAdd(&o[9],  t2.y - sw * ck2.y);
    atomicAdd(&o[10], t2.z - sw * ck2.z);
    atomicAdd(&o[11], t2.w - sw * ck2.w);
    atomicAdd(&o[12], t3.x - sw * ck3.x);
    atomicAdd(&o[13], t3.y - sw * ck3.y);
    atomicAdd(&o[14], t3.z - sw * ck3.z);
    atomicAdd(&o[15], t3.w - sw * ck3.w);
}

extern "C" void kernel_launch(void* const* d_in, const int* in_sizes, int n_in,
                              void* d_out, int out_size, void* d_ws, size_t ws_size,
                              hipStream_t stream) {
    const float* x     = (const float*)d_in[0];
    const float* codes = (const float*)d_in[1];
    const float* scale = (const float*)d_in[2];
    float* out = (float*)d_out;

    hipMemsetAsync(out, 0, K * D * sizeof(float), stream);

    const size_t ws_needed = (size_t)GRID1 * K * D * sizeof(float);  // 16 MB
    if (ws_size >= ws_needed) {
        float* ws = (float*)d_ws;
        enc_partial<<<GRID1, 256, 0, stream>>>(x, codes, scale, ws);
        reduce_kernel<<<64, 256, 0, stream>>>(ws, out);
    } else {
        enc_atomic<<<N / ROWSF, 256, 0, stream>>>(x, codes, scale, out);
    }
}